// Round 10
// baseline (674.943 us; speedup 1.0000x reference)
//
#include <hip/hip_runtime.h>

// ---------------- problem constants ----------------
constexpr int B_ = 8, T_ = 256, H_ = 64, L_ = 3, NB_ = 17, NF_ = 68, HP_ = 6, K_ = 9;
constexpr int FEAT_DIM = NB_ * H_ + NF_ * H_ + H_;   // 5504
constexpr int HT = H_ * T_;                          // 16384 per (b,n)

typedef _Float16 half4_t __attribute__((ext_vector_type(4)));
typedef _Float16 half8_t __attribute__((ext_vector_type(8)));
typedef float f32x16 __attribute__((ext_vector_type(16)));
typedef float f32x4 __attribute__((ext_vector_type(4)));

// ---------------- workspace layout (float units); activations f16 [bn][t][o] ----------------
constexpr size_t SZ_AB = (size_t)B_ * NB_ * HT;
constexpr size_t SZ_AF = (size_t)B_ * NF_ * HT;
constexpr size_t OFF_TB   = 0;
constexpr size_t OFF_TF   = OFF_TB + SZ_AB / 2;
constexpr size_t OFF_W3   = OFF_TF + SZ_AF / 2;      // 4 conv sets x 110592 f16
constexpr size_t OFF_GW3  = OFF_W3 + 4 * 55296;      // 2 x 12288 f16
constexpr size_t OFF_B2   = OFF_GW3 + 2 * 6144;      // 4 x 192 f32
constexpr size_t OFF_FEAT = OFF_B2 + 768;            // 8x5504 f32
constexpr size_t OFF_P1   = OFF_FEAT + (size_t)B_ * FEAT_DIM;

struct ConvPrepSet { const float *w, *tb, *g, *bb, *m, *v; };

// ---------------- all pointers in one arg struct ----------------
struct Args {
    const float *body_kps, *face_kps, *head_pose, *body_adj, *face_adj;
    const float *body_pw, *body_pb, *face_pw, *face_pb, *head_w, *head_b;
    ConvPrepSet sb1, sb2, sf1, sf2;
    const float *b_gcw, *f_gcw, *b_gcb, *f_gcb;
    const float *fus1_w, *fus1_b, *fus2_w, *fus2_b, *fus3_w, *fus3_b, *fus4_w, *fus4_b;
    _Float16 *TrB, *TrF;
    _Float16 *W3, *GW3;
    float *B2, *p1, *feat;
    float *out;
};

// ---------------- small helpers ----------------
__device__ __forceinline__ half8_t ld_b8(const _Float16* p) {
    half4_t lo = *(const half4_t*)p;
    half4_t hi = *(const half4_t*)(p + 4);
    return __builtin_shufflevector(lo, hi, 0, 1, 2, 3, 4, 5, 6, 7);
}

__device__ __forceinline__ void st_b8(_Float16* p, half8_t v) {
    half4_t lo, hi;
#pragma unroll
    for (int j = 0; j < 4; ++j) { lo[j] = v[j]; hi[j] = v[4 + j]; }
    *(half4_t*)p = lo;
    *(half4_t*)(p + 4) = hi;
}

// ---------------- prep: fold BN into conv W; gcw pack; zero p1/feat ----------------
__global__ __launch_bounds__(256) void prep_k(Args A) {
    int blk = blockIdx.x;
    int tid = threadIdx.x;
    if (blk < 1728) {                       // conv-weight fold: 4 sets x 432 blocks
        int set = blk / 432;
        int bx = blk % 432;
        ConvPrepSet s = (set == 0) ? A.sb1 : (set == 1) ? A.sb2 : (set == 2) ? A.sf1 : A.sf2;
        int idx = bx * 256 + tid;           // < 110592
        int k = idx % K_; int r = idx / K_;
        int i = r % H_; r /= H_;
        int o = r % H_; int l = r / H_;
        float sc = s.g[l * H_ + o] * rsqrtf(s.v[l * H_ + o] + 1e-5f);
        A.W3[(size_t)set * 110592 + ((((l * K_ + k) * 8 + (i >> 3)) * H_ + o) * 8) + (i & 7)]
            = (_Float16)(s.w[idx] * sc);
        if (i == 0 && k == 0)
            A.B2[set * 192 + l * H_ + o] =
                s.tb[l * H_ + o] * sc + s.bb[l * H_ + o] - s.m[l * H_ + o] * sc;
    } else if (blk < 1824) {                // gc-weight pack: 2 sets x 48 blocks
        int set = (blk - 1728) / 48;
        int bx = (blk - 1728) % 48;
        const float* gw = set ? A.f_gcw : A.b_gcw;
        int idx = bx * 256 + tid;           // < 12288
        int o = idx % H_; int r = idx / H_;
        int c = r % H_; int l = r / H_;
        A.GW3[(size_t)set * 12288 + (((l * 8 + (c >> 3)) * H_ + o) * 8) + (c & 7)]
            = (_Float16)gw[idx];
    } else {                                // zero p1 + feat
        int idx = (blk - 1824) * 256 + tid;
        if (idx < 2048) {
            A.p1[idx] = 0.f;
        } else if (idx < 2048 + B_ * FEAT_DIM) {
            A.feat[idx - 2048] = 0.f;
        }
    }
}

// ---------------- projection -> trunk f16 [bn][t][o]; tail blocks do head stream ----------------
__global__ __launch_bounds__(256) void proj_k(Args A) {
    int blk = blockIdx.x;
    int tid = threadIdx.x;
    if (blk >= 680) {               // head stream: 8 blocks
        int b = blk - 680;
        if (tid < 64) {
            int c = tid;
            float w0 = A.head_w[c], w1 = A.head_w[64 + c], w2 = A.head_w[128 + c],
                  w3 = A.head_w[192 + c], w4 = A.head_w[256 + c], w5 = A.head_w[320 + c];
            float bias = A.head_b[c];
            float acc = 0.f;
            for (int t = 0; t < T_; ++t) {
                const float* xr = A.head_pose + ((size_t)b * T_ + t) * HP_;
                float s = fmaf(xr[0], w0, fmaf(xr[1], w1, fmaf(xr[2], w2,
                          fmaf(xr[3], w3, fmaf(xr[4], w4, fmaf(xr[5], w5, bias))))));
                acc += fmaxf(s, 0.f);
            }
            A.feat[(size_t)b * FEAT_DIM + NB_ * H_ + NF_ * H_ + c] = acc * (1.f / 256.f);
        }
        return;
    }
    bool isB = blk < B_ * NB_;
    int bn = isB ? blk : blk - B_ * NB_;
    const float* kps = isB ? A.body_kps : A.face_kps;
    const float* pw  = isB ? A.body_pw  : A.face_pw;
    const float* pb  = isB ? A.body_pb  : A.face_pb;
    _Float16* out = isB ? A.TrB : A.TrF;
    int N = isB ? NB_ : NF_;
    int b = bn / N, n = bn % N;
    int t = tid;
    float x0 = kps[((size_t)b * T_ + t) * (N * 2) + n * 2 + 0];
    float x1 = kps[((size_t)b * T_ + t) * (N * 2) + n * 2 + 1];
    _Float16* ob = out + (size_t)bn * HT + (size_t)t * H_;
#pragma unroll
    for (int cg2 = 0; cg2 < 8; ++cg2) {
        half8_t v;
#pragma unroll
        for (int j = 0; j < 8; ++j) {
            int c = cg2 * 8 + j;
            v[j] = (_Float16)fmaf(x0, pw[c], fmaf(x1, pw[H_ + c], pb[c]));
        }
        *(half8_t*)(ob + cg2 * 8) = v;
    }
}

// ---- G-row placement: G[n][g] (g in [0,24)) packed into dead TR rows + GX spill ----
__device__ __forceinline__ _Float16* GrowPtr(_Float16* TRr, _Float16* GXr, int n, int g) {
    return (g < 8)  ? TRr + ((size_t)(n * 32 + g) * 68)
         : (g < 16) ? GXr + ((size_t)(n * 8 + (g - 8)) * 68)
                    : TRr + ((size_t)(n * 32 + g + 8) * 68);
}

// ---------------- fused layer kernel: cm + adjmix + c2 per (batch, component, t-chunk16) ----------------
// LDS regions (f16 elems): TR [NG][32][68] (0..36991), SUP [NG][24][68] (36992..64735),
//                          GX [NG][8][68] (64736..73983). Residual stays in TR rows [8,24).
template <bool LAST>
__global__ __launch_bounds__(256, 1) void layer_k(Args A, int l) {
    __shared__ __align__(16) _Float16 LS[73984];
    __shared__ float nbC[17 * 6];
    __shared__ short nbI[17 * 6];
    __shared__ int   degA[17];
    _Float16* TRr  = LS;
    _Float16* SUPr = LS + 36992;
    _Float16* GXr  = LS + 64736;

    int tid = threadIdx.x;
    int blk = blockIdx.x;
    int b  = blk & 7;                 // XCD affinity: batch -> XCD
    int u  = blk >> 3;
    int gid = u >> 4, tc = u & 15;

    // components: gid0 = body(17); gid1..9 = face chains/rings
    const int nbT[10] = {0, 0, 17, 22, 27, 31, 36, 42, 48, 60};
    const int ngT[10] = {17, 17, 5, 5, 4, 5, 6, 6, 12, 8};
    bool isB = (gid == 0);
    int nb = nbT[gid], NG = ngT[gid];
    int N  = isB ? NB_ : NF_;

    const _Float16* TrG = isB ? A.TrB : A.TrF;
    _Float16* TrOut = isB ? A.TrB : A.TrF;
    const half8_t* w1 = (const half8_t*)(A.W3 + (isB ? 0 : 221184)) + (size_t)l * (K_ * 8 * H_);
    const half8_t* w2 = (const half8_t*)(A.W3 + (isB ? 110592 : 331776)) + (size_t)l * (K_ * 8 * H_);
    const half8_t* gw = (const half8_t*)(A.GW3 + (isB ? 0 : 12288)) + (size_t)l * (8 * H_);
    const float* b1l  = (isB ? A.B2 : A.B2 + 384) + l * H_;
    const float* b2l  = (isB ? A.B2 + 192 : A.B2 + 576) + l * H_;
    const float* gcbl = (isB ? A.b_gcb : A.f_gcb) + l * H_;
    const float* adjG = isB ? A.body_adj : A.face_adj;
    int fbase = isB ? 0 : NB_ * H_;

    // neighbor lists (coefs from the raw normalized adjacency; component-local)
    if (tid < NG) {
        const float* arow = adjG + (size_t)(nb + tid) * N;
        int d = 0;
        for (int m = 0; m < NG; ++m) {
            float c = arow[nb + m];
            if (c != 0.f) { nbI[tid * 6 + d] = (short)m; nbC[tid * 6 + d] = c; ++d; }
        }
        degA[tid] = d;
    }
    // stage Tr[NG][t-8..t+24)][64] -> TR (pitch 68), OOB rows zero
    for (int i = 0; i < NG; ++i) {
        int v = i * 256 + tid;
        int n = v >> 8, rr = v & 255;
        int row = rr >> 3, cg = rr & 7;
        int t = tc * 16 + row - 8;
        half8_t hv;
        if (t >= 0 && t < T_) {
            hv = *(const half8_t*)(TrG + ((size_t)(b * N + nb + n) * T_ + t) * H_ + cg * 8);
        } else {
#pragma unroll
            for (int j = 0; j < 8; ++j) hv[j] = (_Float16)0.f;
        }
        st_b8(&TRr[(size_t)(n * 32 + row) * 68 + cg * 8], hv);
    }
    __syncthreads();

    int ln = tid & 63;
    int w = __builtin_amdgcn_readfirstlane(tid >> 6);
    int ln31 = ln & 31, kg = ln >> 5;
    int sE = (ln31 < 24) ? ln31 : 23;

    // ---- phase 1: per node (wave-owned): conv1+bn+relu -> mid; channel mix -> SupF (in place)
    for (int n = w; n < NG; n += 4) {
        f32x16 a0c, a1c;
#pragma unroll
        for (int r = 0; r < 16; ++r) { a0c[r] = 0.f; a1c[r] = 0.f; }
        const _Float16* base = &TRr[(size_t)(n * 32 + sE) * 68];
#pragma unroll
        for (int tap = 0; tap < K_; ++tap) {
#pragma unroll
            for (int ks = 0; ks < 4; ++ks) {
                int i8 = ks * 2 + kg;
                half8_t a0 = w1[(tap * 8 + i8) * H_ + ln31];
                half8_t a1 = w1[(tap * 8 + i8) * H_ + 32 + ln31];
                half8_t bf = ld_b8(base + tap * 68 + i8 * 8);
                a0c = __builtin_amdgcn_mfma_f32_32x32x16_f16(a0, bf, a0c, 0, 0, 0);
                a1c = __builtin_amdgcn_mfma_f32_32x32x16_f16(a1, bf, a1c, 0, 0, 0);
            }
        }
        // mid = relu(conv + b1) -> SUP[n][s][o], s = ln31 < 24
        if (ln31 < 24) {
            _Float16* mrow = &SUPr[(size_t)(n * 24 + ln31) * 68];
#pragma unroll
            for (int ot = 0; ot < 2; ++ot) {
#pragma unroll
                for (int rg = 0; rg < 4; ++rg) {
                    int o0 = ot * 32 + rg * 8 + kg * 4;
                    f32x4 bv = *(const f32x4*)(b1l + o0);
                    half4_t hv;
#pragma unroll
                    for (int j = 0; j < 4; ++j) {
                        float y = (ot ? a1c[rg * 4 + j] : a0c[rg * 4 + j]) + bv[j];
                        hv[j] = (_Float16)fmaxf(y, 0.f);
                    }
                    *(half4_t*)(mrow + o0) = hv;
                }
            }
        }
        // channel mix (K=64), in-place per node (same wave -> ordered)
        f32x16 m0, m1;
#pragma unroll
        for (int r = 0; r < 16; ++r) { m0[r] = 0.f; m1[r] = 0.f; }
        const _Float16* mbase = &SUPr[(size_t)(n * 24 + sE) * 68];
#pragma unroll
        for (int ks = 0; ks < 4; ++ks) {
            int i8 = ks * 2 + kg;
            half8_t a0 = gw[i8 * H_ + ln31];
            half8_t a1 = gw[i8 * H_ + 32 + ln31];
            half8_t bf = ld_b8(mbase + i8 * 8);
            m0 = __builtin_amdgcn_mfma_f32_32x32x16_f16(a0, bf, m0, 0, 0, 0);
            m1 = __builtin_amdgcn_mfma_f32_32x32x16_f16(a1, bf, m1, 0, 0, 0);
        }
        if (ln31 < 24) {
            _Float16* srow = &SUPr[(size_t)(n * 24 + ln31) * 68];
#pragma unroll
            for (int ot = 0; ot < 2; ++ot) {
#pragma unroll
                for (int rg = 0; rg < 4; ++rg) {
                    int o0 = ot * 32 + rg * 8 + kg * 4;
                    half4_t hv;
#pragma unroll
                    for (int j = 0; j < 4; ++j)
                        hv[j] = (_Float16)(ot ? m1[rg * 4 + j] : m0[rg * 4 + j]);
                    *(half4_t*)(srow + o0) = hv;
                }
            }
        }
    }
    __syncthreads();   // all SupF visible

    // ---- phase 2: per node-pair (wave-owned): adjmix (VALU, sparse) -> G; c2 paired MFMA -> out
    int P = (NG + 1) >> 1;
    int nf = ln31 >> 4, sc = ln31 & 15;
    for (int p = w; p < P; p += 4) {
        int n0 = 2 * p;
        bool two = (n0 + 1 < NG);
        // adjmix: G[n] = relu(sum_m a[n][m]*SupF[m] + gcb), rows s in [0,24)
        for (int q = 0; q < 2; ++q) {
            if (q == 1 && !two) break;
            int n = n0 + q;
            int dg = degA[n];
            for (int it = 0; it < 12; ++it) {
                int v = it * 64 + ln;
                int s = v >> 5, cp = v & 31, c = cp * 2;
                float v0 = 0.f, v1 = 0.f;
                for (int j = 0; j < dg; ++j) {
                    int m = nbI[n * 6 + j];
                    float cf = nbC[n * 6 + j];
                    const _Float16* sp = &SUPr[(size_t)(m * 24 + s) * 68 + c];
                    v0 = fmaf(cf, (float)sp[0], v0);
                    v1 = fmaf(cf, (float)sp[1], v1);
                }
                v0 = fmaxf(v0 + gcbl[c], 0.f);
                v1 = fmaxf(v1 + gcbl[c + 1], 0.f);
                _Float16* gp = GrowPtr(TRr, GXr, n, s) + c;
                gp[0] = (_Float16)v0;
                gp[1] = (_Float16)v1;
            }
        }
        // c2: paired cols (nf = node offset, sc = out t); K-loop over G rows g = sc+tap
        int node = n0 + (two ? nf : 0);
        f32x16 a0c, a1c;
#pragma unroll
        for (int r = 0; r < 16; ++r) { a0c[r] = 0.f; a1c[r] = 0.f; }
#pragma unroll
        for (int tap = 0; tap < K_; ++tap) {
#pragma unroll
            for (int ks = 0; ks < 4; ++ks) {
                int i8 = ks * 2 + kg;
                half8_t a0 = w2[(tap * 8 + i8) * H_ + ln31];
                half8_t a1 = w2[(tap * 8 + i8) * H_ + 32 + ln31];
                half8_t bf = ld_b8(GrowPtr(TRr, GXr, node, sc + tap) + i8 * 8);
                a0c = __builtin_amdgcn_mfma_f32_32x32x16_f16(a0, bf, a0c, 0, 0, 0);
                a1c = __builtin_amdgcn_mfma_f32_32x32x16_f16(a1, bf, a1c, 0, 0, 0);
            }
        }
        bool valid = two || (nf == 0);
        const _Float16* rrow = &TRr[(size_t)(node * 32 + 8 + sc) * 68];
        if (!LAST) {
            if (valid) {
                _Float16* og = TrOut + ((size_t)(b * N + nb + node) * T_ + tc * 16 + sc) * H_;
#pragma unroll
                for (int ot = 0; ot < 2; ++ot) {
#pragma unroll
                    for (int rg = 0; rg < 4; ++rg) {
                        int o0 = ot * 32 + rg * 8 + kg * 4;
                        f32x4 bv = *(const f32x4*)(b2l + o0);
                        half4_t rv = *(const half4_t*)(rrow + o0);
                        half4_t hv;
#pragma unroll
                        for (int j = 0; j < 4; ++j) {
                            float y = (ot ? a1c[rg * 4 + j] : a0c[rg * 4 + j])
                                    + bv[j] + (float)rv[j];
                            hv[j] = (_Float16)y;
                        }
                        *(half4_t*)(og + o0) = hv;
                    }
                }
            }
        } else {
            // pool over this chunk's 16 t (lanes sc of each 16-group)
            float sv[2][16];
#pragma unroll
            for (int ot = 0; ot < 2; ++ot) {
#pragma unroll
                for (int rg = 0; rg < 4; ++rg) {
                    int o0 = ot * 32 + rg * 8 + kg * 4;
                    f32x4 bv = *(const f32x4*)(b2l + o0);
                    half4_t rv = *(const half4_t*)(rrow + o0);
#pragma unroll
                    for (int j = 0; j < 4; ++j) {
                        int r = rg * 4 + j;
                        float y = valid ? ((ot ? a1c[r] : a0c[r]) + bv[j] + (float)rv[j]) : 0.f;
#pragma unroll
                        for (int off = 1; off < 16; off <<= 1) y += __shfl_xor(y, off);
                        sv[ot][r] = y;
                    }
                }
            }
            if (sc == 0 && valid) {
#pragma unroll
                for (int ot = 0; ot < 2; ++ot)
#pragma unroll
                    for (int r = 0; r < 16; ++r) {
                        int o = ot * 32 + (r & 3) + 8 * (r >> 2) + 4 * kg;
                        atomicAdd(&A.feat[(size_t)b * FEAT_DIM + fbase + (nb + node) * H_ + o],
                                  sv[ot][r] * (1.f / 256.f));
                    }
            }
        }
    }
}

// ---------------- fusion layer 1 (5504 -> 256), split-K, all 8 batches per block ----------------
__global__ __launch_bounds__(256) void fus1_k(Args A) {
    __shared__ float fv[8][64];
    int blk = blockIdx.x;          // 86 = 43 ic * 2 khalf
    int ic = blk >> 1, kh = blk & 1;
    int base = ic * 128 + kh * 64;
    int tid = threadIdx.x;
    for (int u = tid; u < 8 * 64; u += 256) {
        int b = u >> 6, j = u & 63;
        fv[b][j] = A.feat[(size_t)b * FEAT_DIM + base + j];
    }
    __syncthreads();
    float acc[8];
#pragma unroll
    for (int b = 0; b < 8; ++b) acc[b] = 0.f;
    const float* wb = A.fus1_w + (size_t)base * 256 + tid;
    for (int i = 0; i < 64; ++i) {
        float wv = wb[(size_t)i * 256];
#pragma unroll
        for (int b = 0; b < 8; ++b) acc[b] = fmaf(fv[b][i], wv, acc[b]);
    }
#pragma unroll
    for (int b = 0; b < 8; ++b) atomicAdd(&A.p1[b * 256 + tid], acc[b]);
}

// ---------------- fusion tail ----------------
__global__ __launch_bounds__(256) void fus_tail_k(Args A) {
    __shared__ float s1[256], s2[128], s3[64];
    int b = blockIdx.x, tid = threadIdx.x;
    s1[tid] = fmaxf(A.p1[b * 256 + tid] + A.fus1_b[tid], 0.f);
    __syncthreads();
    if (tid < 128) {
        float acc = A.fus2_b[tid];
        for (int i = 0; i < 256; ++i) acc = fmaf(s1[i], A.fus2_w[i * 128 + tid], acc);
        s2[tid] = fmaxf(acc, 0.f);
    }
    __syncthreads();
    if (tid < 64) {
        float acc = A.fus3_b[tid];
        for (int i = 0; i < 128; ++i) acc = fmaf(s2[i], A.fus3_w[i * 64 + tid], acc);
        s3[tid] = fmaxf(acc, 0.f);
    }
    __syncthreads();
    if (tid < 5) {
        float acc = A.fus4_b[tid];
        for (int i = 0; i < 64; ++i) acc = fmaf(s3[i], A.fus4_w[i * 5 + tid], acc);
        A.out[b * 5 + tid] = acc;
    }
}

// ---------------- launch ----------------
extern "C" void kernel_launch(void* const* d_in, const int* in_sizes, int n_in,
                              void* d_out, int out_size, void* d_ws, size_t ws_size,
                              hipStream_t stream) {
    float* ws = (float*)d_ws;

    Args A;
    A.body_kps = (const float*)d_in[0];
    A.face_kps = (const float*)d_in[1];
    A.head_pose = (const float*)d_in[2];
    A.body_adj = (const float*)d_in[3];
    A.face_adj = (const float*)d_in[4];
    A.body_pw = (const float*)d_in[5];
    A.body_pb = (const float*)d_in[6];
    A.face_pw = (const float*)d_in[7];
    A.face_pb = (const float*)d_in[8];
    A.head_w = (const float*)d_in[9];
    A.head_b = (const float*)d_in[10];
    A.sb1 = ConvPrepSet{(const float*)d_in[11], (const float*)d_in[12], (const float*)d_in[13],
                        (const float*)d_in[14], (const float*)d_in[15], (const float*)d_in[16]};
    A.b_gcw = (const float*)d_in[17];
    A.b_gcb = (const float*)d_in[18];
    A.sb2 = ConvPrepSet{(const float*)d_in[19], (const float*)d_in[20], (const float*)d_in[21],
                        (const float*)d_in[22], (const float*)d_in[23], (const float*)d_in[24]};
    A.sf1 = ConvPrepSet{(const float*)d_in[25], (const float*)d_in[26], (const float*)d_in[27],
                        (const float*)d_in[28], (const float*)d_in[29], (const float*)d_in[30]};
    A.f_gcw = (const float*)d_in[31];
    A.f_gcb = (const float*)d_in[32];
    A.sf2 = ConvPrepSet{(const float*)d_in[33], (const float*)d_in[34], (const float*)d_in[35],
                        (const float*)d_in[36], (const float*)d_in[37], (const float*)d_in[38]};
    A.fus1_w = (const float*)d_in[39]; A.fus1_b = (const float*)d_in[40];
    A.fus2_w = (const float*)d_in[41]; A.fus2_b = (const float*)d_in[42];
    A.fus3_w = (const float*)d_in[43]; A.fus3_b = (const float*)d_in[44];
    A.fus4_w = (const float*)d_in[45]; A.fus4_b = (const float*)d_in[46];

    A.TrB  = (_Float16*)(ws + OFF_TB);
    A.TrF  = (_Float16*)(ws + OFF_TF);
    A.W3   = (_Float16*)(ws + OFF_W3);
    A.GW3  = (_Float16*)(ws + OFF_GW3);
    A.B2   = ws + OFF_B2;
    A.feat = ws + OFF_FEAT;
    A.p1   = ws + OFF_P1;
    A.out  = (float*)d_out;

    prep_k<<<2038, 256, 0, stream>>>(A);
    proj_k<<<688, 256, 0, stream>>>(A);                 // proj + head
    layer_k<false><<<1280, 256, 0, stream>>>(A, 0);     // fused cm+adjmix+c2, layer 0
    layer_k<false><<<1280, 256, 0, stream>>>(A, 1);
    layer_k<true><<<1280, 256, 0, stream>>>(A, 2);      // + temporal mean-pool -> feat
    fus1_k<<<86, 256, 0, stream>>>(A);
    fus_tail_k<<<8, 256, 0, stream>>>(A);
}

// Round 11
// 501.142 us; speedup vs baseline: 1.3468x; 1.3468x over previous
//
#include <hip/hip_runtime.h>

// ---------------- problem constants ----------------
constexpr int B_ = 8, T_ = 256, H_ = 64, L_ = 3, NB_ = 17, NF_ = 68, HP_ = 6, K_ = 9;
constexpr int FEAT_DIM = NB_ * H_ + NF_ * H_ + H_;   // 5504
constexpr int HT = H_ * T_;                          // 16384 per (b,n)

typedef _Float16 half4_t __attribute__((ext_vector_type(4)));
typedef _Float16 half8_t __attribute__((ext_vector_type(8)));
typedef float f32x16 __attribute__((ext_vector_type(16)));
typedef float f32x4 __attribute__((ext_vector_type(4)));

// ---------------- workspace layout (float units); activations f16 [bn][t][o] ----------------
constexpr size_t SZ_AB = (size_t)B_ * NB_ * HT;
constexpr size_t SZ_AF = (size_t)B_ * NF_ * HT;
constexpr size_t OFF_TB   = 0;
constexpr size_t OFF_TF   = OFF_TB + SZ_AB / 2;
constexpr size_t OFF_SUPB = OFF_TF + SZ_AF / 2;
constexpr size_t OFF_SUPF = OFF_SUPB + SZ_AB / 2;
constexpr size_t OFF_GB   = OFF_SUPF + SZ_AF / 2;
constexpr size_t OFF_GF   = OFF_GB + SZ_AB / 2;
constexpr size_t OFF_W3   = OFF_GF + SZ_AF / 2;      // 4 conv sets x 110592 f16
constexpr size_t OFF_GW3  = OFF_W3 + 4 * 55296;      // 2 x 12288 f16
constexpr size_t OFF_B2   = OFF_GW3 + 2 * 6144;      // 4 x 192 f32
constexpr size_t OFF_ADJPB= OFF_B2 + 768;            // 32x32 f16
constexpr size_t OFF_ADJPF= OFF_ADJPB + 512;         // 96x80 f16
constexpr size_t OFF_FEAT = OFF_ADJPF + 3840;        // 8x5504 f32
constexpr size_t OFF_P1   = OFF_FEAT + (size_t)B_ * FEAT_DIM;

struct ConvPrepSet { const float *w, *tb, *g, *bb, *m, *v; };

// ---------------- all pointers in one arg struct ----------------
struct Args {
    const float *body_kps, *face_kps, *head_pose, *body_adj, *face_adj;
    const float *body_pw, *body_pb, *face_pw, *face_pb, *head_w, *head_b;
    ConvPrepSet sb1, sb2, sf1, sf2;
    const float *b_gcw, *f_gcw, *b_gcb, *f_gcb;
    const float *fus1_w, *fus1_b, *fus2_w, *fus2_b, *fus3_w, *fus3_b, *fus4_w, *fus4_b;
    _Float16 *TrB, *TrF, *SupB, *SupF, *Gb, *Gf;
    _Float16 *W3, *GW3, *adjPB, *adjPF;
    float *B2, *p1, *feat;
    float *out;
};

// ---------------- small helpers ----------------
__device__ __forceinline__ half8_t ld_b8(const _Float16* p) {
    half4_t lo = *(const half4_t*)p;
    half4_t hi = *(const half4_t*)(p + 4);
    return __builtin_shufflevector(lo, hi, 0, 1, 2, 3, 4, 5, 6, 7);
}

__device__ __forceinline__ void st_b8(_Float16* p, half8_t v) {
    half4_t lo, hi;
#pragma unroll
    for (int j = 0; j < 4; ++j) { lo[j] = v[j]; hi[j] = v[4 + j]; }
    *(half4_t*)p = lo;
    *(half4_t*)(p + 4) = hi;
}

// stage f16 [t][o] 64-t chunk -> Xs[72][68]; rows 0..71 = t (tc*64-4 .. tc*64+67), OOB=0
__device__ __forceinline__ void stage_chunk64(const _Float16* __restrict__ xb,
                                              _Float16* __restrict__ Xs, int tc, int tid) {
    for (int u = tid; u < 72 * 8; u += 256) {
        int row = u >> 3, c = u & 7;
        int t = tc * 64 + row - 4;
        half8_t v;
        if (t >= 0 && t < T_) {
            v = *(const half8_t*)(xb + (size_t)t * H_ + c * 8);
        } else {
#pragma unroll
            for (int j = 0; j < 8; ++j) v[j] = (_Float16)0.f;
        }
        st_b8(&Xs[row * 68 + c * 8], v);
    }
}

// stage residual 64-t chunk rows [t][o] -> Rs[64][68] (t = tc*64 .. tc*64+63)
__device__ __forceinline__ void stage_res64(const _Float16* __restrict__ xb,
                                            _Float16* __restrict__ Rs, int tc, int tid) {
    for (int u = tid; u < 64 * 8; u += 256) {
        int row = u >> 3, c = u & 7;
        half8_t v = *(const half8_t*)(xb + (size_t)(tc * 64 + row) * H_ + c * 8);
        st_b8(&Rs[row * 68 + c * 8], v);
    }
}

// ---- register-staged tile (dbuf kernels): 72 rows x 8 col-groups of b128
struct SReg { half8_t v[3]; };

__device__ __forceinline__ void issue_stage(const _Float16* __restrict__ xb, int tc, int tid,
                                            SReg& S) {
#pragma unroll
    for (int k = 0; k < 3; ++k) {
        int u = k * 256 + tid;
        if (u < 576) {
            int row = u >> 3, c = u & 7;
            int t = tc * 64 + row - 4;
            if (t >= 0 && t < T_) {
                S.v[k] = *(const half8_t*)(xb + (size_t)t * H_ + c * 8);
            } else {
#pragma unroll
                for (int j = 0; j < 8; ++j) S.v[k][j] = (_Float16)0.f;
            }
        }
    }
}

__device__ __forceinline__ void write_stage(_Float16* __restrict__ Xs, int tid, const SReg& S) {
#pragma unroll
    for (int k = 0; k < 3; ++k) {
        int u = k * 256 + tid;
        if (u < 576) {
            int row = u >> 3, c = u & 7;
            st_b8(&Xs[row * 68 + c * 8], S.v[k]);
        }
    }
}

// ---- residual fetch direct to regs (consumed at epilogue, overlaps K-loop)
struct RReg { half4_t r[4]; };

__device__ __forceinline__ void issue_res(const _Float16* __restrict__ tb, int tc, int trow,
                                          int ln31, int kg, int ot, RReg& R) {
    const _Float16* rr = tb + (size_t)(tc * 64 + trow + ln31) * H_ + ot * 32 + kg * 4;
#pragma unroll
    for (int rg = 0; rg < 4; ++rg)
        R.r[rg] = *(const half4_t*)(rr + rg * 8);
}

// conv K-loop: 9 taps x 4 ks -> acc, wave covers 32 t-cols x 32 o (one o-tile)
__device__ __forceinline__ void conv_kloop(const half8_t* __restrict__ wl,
                                           const _Float16* __restrict__ Xs,
                                           int trow, int ln31, int kg, int ot,
                                           f32x16& acc) {
    const _Float16* xr0 = Xs + (size_t)(trow + ln31) * 68;
#pragma unroll
    for (int tap = 0; tap < K_; ++tap) {
#pragma unroll
        for (int ks = 0; ks < 4; ++ks) {
            int i8 = ks * 2 + kg;
            half8_t a = wl[(tap * 8 + i8) * H_ + ot * 32 + ln31];
            half8_t bf = ld_b8(xr0 + tap * 68 + i8 * 8);
            acc = __builtin_amdgcn_mfma_f32_32x32x16_f16(a, bf, acc, 0, 0, 0);
        }
    }
}

// ---------------- convmix core: Xs pre-staged -> sup 64-t chunk ----------------
// 4 waves: wave (ts = w&1, ot = w>>1) covers t-sub 32ts..32ts+32, o-tile 32ot..
__device__ void convmix_core(const half8_t* __restrict__ wl,   // w1 + layer offset
                             const float* __restrict__ b1l,    // b1 + l*H_
                             const half8_t* __restrict__ gl,   // gc + layer offset
                             _Float16* __restrict__ supb,      // sup + bn*HT
                             int tc, _Float16* __restrict__ Xs, int tid) {
    int ln = tid & 63;
    int w = __builtin_amdgcn_readfirstlane(tid >> 6);
    int ln31 = ln & 31, kg = ln >> 5;
    int ts = w & 1, ot = w >> 1;
    int trow = ts * 32;

    f32x16 acc;
#pragma unroll
    for (int r = 0; r < 16; ++r) acc[r] = 0.f;

    conv_kloop(wl, Xs, trow, ln31, kg, ot, acc);
    __syncthreads();

    // conv1 epilogue: bias+relu -> mid row Xs[4+t][o] (wave-own (ts,ot) region)
    _Float16* mrow = Xs + (size_t)(4 + trow + ln31) * 68;
#pragma unroll
    for (int rg = 0; rg < 4; ++rg) {
        int o0 = ot * 32 + rg * 8 + kg * 4;
        f32x4 bv = *(const f32x4*)(b1l + o0);
        half4_t hv;
#pragma unroll
        for (int j = 0; j < 4; ++j)
            hv[j] = (_Float16)fmaxf(acc[rg * 4 + j] + bv[j], 0.f);
        *(half4_t*)(mrow + o0) = hv;
    }
    __syncthreads();

    // channel mix (K=64): reads full mid rows (both o-halves)
    f32x16 acc2;
#pragma unroll
    for (int r = 0; r < 16; ++r) acc2[r] = 0.f;
#pragma unroll
    for (int ks = 0; ks < 4; ++ks) {
        int i8 = ks * 2 + kg;
        half8_t a = gl[i8 * H_ + ot * 32 + ln31];
        half8_t bf = ld_b8(mrow + i8 * 8);
        acc2 = __builtin_amdgcn_mfma_f32_32x32x16_f16(a, bf, acc2, 0, 0, 0);
    }
    __syncthreads();   // other o-wave may still be reading these rows

    // write acc2 -> mid rows (wave-own region), then coalesced b128 copy-out
#pragma unroll
    for (int rg = 0; rg < 4; ++rg) {
        int o0 = ot * 32 + rg * 8 + kg * 4;
        half4_t hv;
#pragma unroll
        for (int j = 0; j < 4; ++j)
            hv[j] = (_Float16)acc2[rg * 4 + j];
        *(half4_t*)(mrow + o0) = hv;
    }
    __syncthreads();
    _Float16* gout = supb + (size_t)(tc * 64) * H_;
    const _Float16* srow = Xs + 4 * 68;
#pragma unroll
    for (int k2 = 0; k2 < 2; ++k2) {
        int u = k2 * 256 + tid;     // 512 units: 64 rows x 8 col-groups
        int r = u >> 3, c = u & 7;
        half8_t v = ld_b8(srow + r * 68 + c * 8);
        *(half8_t*)(gout + (size_t)r * H_ + c * 8) = v;
    }
}

// ---------------- prep: fold BN into conv W; gcw pack; adj pad; zero p1/feat ----------------
__global__ __launch_bounds__(256) void prep_k(Args A) {
    int blk = blockIdx.x;
    int tid = threadIdx.x;
    if (blk < 1728) {                       // conv-weight fold: 4 sets x 432 blocks
        int set = blk / 432;
        int bx = blk % 432;
        ConvPrepSet s = (set == 0) ? A.sb1 : (set == 1) ? A.sb2 : (set == 2) ? A.sf1 : A.sf2;
        int idx = bx * 256 + tid;           // < 110592
        int k = idx % K_; int r = idx / K_;
        int i = r % H_; r /= H_;
        int o = r % H_; int l = r / H_;
        float sc = s.g[l * H_ + o] * rsqrtf(s.v[l * H_ + o] + 1e-5f);
        A.W3[(size_t)set * 110592 + ((((l * K_ + k) * 8 + (i >> 3)) * H_ + o) * 8) + (i & 7)]
            = (_Float16)(s.w[idx] * sc);
        if (i == 0 && k == 0)
            A.B2[set * 192 + l * H_ + o] =
                s.tb[l * H_ + o] * sc + s.bb[l * H_ + o] - s.m[l * H_ + o] * sc;
    } else if (blk < 1824) {                // gc-weight pack: 2 sets x 48 blocks
        int set = (blk - 1728) / 48;
        int bx = (blk - 1728) % 48;
        const float* gw = set ? A.f_gcw : A.b_gcw;
        int idx = bx * 256 + tid;           // < 12288
        int o = idx % H_; int r = idx / H_;
        int c = r % H_; int l = r / H_;
        A.GW3[(size_t)set * 12288 + (((l * 8 + (c >> 3)) * H_ + o) * 8) + (c & 7)]
            = (_Float16)gw[idx];
    } else {                                // misc: adj pad + zero p1/feat
        int idx = (blk - 1824) * 256 + tid;
        if (idx < 1024) {
            int m = idx >> 5, k = idx & 31;
            A.adjPB[idx] = (m < NB_ && k < NB_) ? (_Float16)A.body_adj[m * NB_ + k] : (_Float16)0.f;
        } else if (idx < 8704) {
            int j = idx - 1024;
            int m = j / 80, k = j % 80;
            A.adjPF[j] = (m < NF_ && k < NF_) ? (_Float16)A.face_adj[m * NF_ + k] : (_Float16)0.f;
        } else if (idx < 10752) {
            A.p1[idx - 8704] = 0.f;
        } else if (idx < 10752 + B_ * FEAT_DIM) {
            A.feat[idx - 10752] = 0.f;
        }
    }
}

// ---------------- fused proj + convmix(l=0): block = (bn, 64-t chunk) (R6 verbatim) ----------------
__global__ __launch_bounds__(256, 8) void projcm_k(Args A) {
    __shared__ __align__(16) _Float16 Xs[72 * 68];
    int blk = blockIdx.x, tid = threadIdx.x;
    bool isB = blk < 4 * B_ * NB_;
    int j = isB ? blk : blk - 4 * B_ * NB_;
    int bn = j >> 2, tc = j & 3;
    const float* kps = isB ? A.body_kps : A.face_kps;
    const float* pw  = isB ? A.body_pw  : A.face_pw;
    const float* pb  = isB ? A.body_pb  : A.face_pb;
    _Float16* trunk  = isB ? A.TrB : A.TrF;
    int N = isB ? NB_ : NF_;
    int b = bn / N, n = bn % N;

    // proj: fill Xs rows 0..71 (incl. halo recompute); global write for owned rows only
    if (tid < 144) {
        int row = tid >> 1, hf = tid & 1;       // 32 channels per unit
        int t = tc * 64 + row - 4;
        _Float16* xr = Xs + row * 68 + hf * 32;
        if (t >= 0 && t < T_) {
            float x0 = kps[((size_t)b * T_ + t) * (N * 2) + n * 2 + 0];
            float x1 = kps[((size_t)b * T_ + t) * (N * 2) + n * 2 + 1];
            bool own = (row >= 4 && row < 68);
            _Float16* ob = trunk + (size_t)bn * HT + (size_t)t * H_ + hf * 32;
#pragma unroll
            for (int cg2 = 0; cg2 < 4; ++cg2) {
                half8_t v;
#pragma unroll
                for (int jj = 0; jj < 8; ++jj) {
                    int c = hf * 32 + cg2 * 8 + jj;
                    v[jj] = (_Float16)fmaf(x0, pw[c], fmaf(x1, pw[H_ + c], pb[c]));
                }
                st_b8(xr + cg2 * 8, v);
                if (own) *(half8_t*)(ob + cg2 * 8) = v;
            }
        } else {
            half8_t z;
#pragma unroll
            for (int jj = 0; jj < 8; ++jj) z[jj] = (_Float16)0.f;
            st_b8(xr, z);
            st_b8(xr + 8, z);
            st_b8(xr + 16, z);
            st_b8(xr + 24, z);
        }
    }
    __syncthreads();

    const half8_t* w1 = (const half8_t*)(A.W3 + (isB ? 0 : 221184));     // l=0 slice
    const float* b1l  = isB ? A.B2 : A.B2 + 384;
    const half8_t* gl = (const half8_t*)(A.GW3 + (isB ? 0 : 12288));
    _Float16* supb = (isB ? A.SupB : A.SupF) + (size_t)bn * HT;
    convmix_core(w1, b1l, gl, supb, tc, Xs, tid);
}

// ---------------- convmix(l): trunk -> sup; block owns 2 chunks, LDS double-buffer ----------------
__global__ __launch_bounds__(256, 6) void cm_k(Args A, int l) {
    __shared__ __align__(16) _Float16 Xs[2][72 * 68];
    int blk = blockIdx.x, tid = threadIdx.x;
    bool isB = blk < 2 * B_ * NB_;
    int j = isB ? blk : blk - 2 * B_ * NB_;
    int bn = j >> 1, half = j & 1;
    const _Float16* trunk = (isB ? A.TrB : A.TrF) + (size_t)bn * HT;

    const half8_t* w1 = (const half8_t*)(A.W3 + (isB ? 0 : 221184)) + (size_t)l * (K_ * 8 * H_);
    const float* b1l  = (isB ? A.B2 : A.B2 + 384) + l * H_;
    const half8_t* gl = (const half8_t*)(A.GW3 + (isB ? 0 : 12288)) + (size_t)l * (8 * H_);
    _Float16* supb = (isB ? A.SupB : A.SupF) + (size_t)bn * HT;

    {
        SReg S;
        issue_stage(trunk, half * 2, tid, S);
        write_stage(Xs[0], tid, S);
    }
    __syncthreads();

#pragma unroll 1
    for (int i = 0; i < 2; ++i) {
        int tc = half * 2 + i;
        SReg Sn;
        if (i == 0) issue_stage(trunk, tc + 1, tid, Sn);   // loads in flight across K-loop
        convmix_core(w1, b1l, gl, supb, tc, Xs[i], tid);
        if (i == 0) {
            write_stage(Xs[1], tid, Sn);                   // idle buffer
            __syncthreads();
        }
    }
}

// ---------------- adjmix: out = relu(adj @ sup + gb), LDS-transposed b128 output ----------------
template <int N, int MT, int KS>
__device__ void adjmix_impl(const _Float16* __restrict__ sup,
                            const half8_t* __restrict__ adjP,
                            const float* __restrict__ gb,
                            _Float16* __restrict__ out,
                            int blk, int l, _Float16* Ls, int tid) {
    constexpr int KP = KS * 16;
    constexpr int PITCH = KP + 4;
    int b = blk >> 7, cb = blk & 127;
    int colbase = cb * 128;

    for (int u = tid; u < KP * 16; u += 256) {
        int n = u >> 4, cs = u & 15;
        half8_t v;
        if (n < N) v = *(const half8_t*)(sup + (size_t)(b * N + n) * HT + colbase + cs * 8);
        else {
#pragma unroll
            for (int j = 0; j < 8; ++j) v[j] = (_Float16)0.f;
        }
#pragma unroll
        for (int j = 0; j < 8; ++j) Ls[(cs * 8 + j) * PITCH + n] = v[j];
    }
    __syncthreads();

    int ln = tid & 63;
    int w = __builtin_amdgcn_readfirstlane(tid >> 6);
    int ln31 = ln & 31, kg = ln >> 5;
    int colL = w * 32 + ln31;

    f32x16 acc[MT];
#pragma unroll
    for (int mt = 0; mt < MT; ++mt)
#pragma unroll
        for (int r = 0; r < 16; ++r) acc[mt][r] = 0.f;

#pragma unroll
    for (int ks = 0; ks < KS; ++ks) {
        half8_t bf = ld_b8(&Ls[colL * PITCH + ks * 16 + kg * 8]);
#pragma unroll
        for (int mt = 0; mt < MT; ++mt) {
            half8_t af = adjP[(size_t)(mt * 32 + ln31) * (KP / 8) + ks * 2 + kg];
            acc[mt] = __builtin_amdgcn_mfma_f32_32x32x16_f16(af, bf, acc[mt], 0, 0, 0);
        }
    }
    __syncthreads();   // staging reads done; reuse Ls as [m][132] out-transpose buffer

    float gbv = gb[l * H_ + (colL & 63)];   // [t][o] layout: o = col & 63
#pragma unroll
    for (int mt = 0; mt < MT; ++mt) {
#pragma unroll
        for (int r = 0; r < 16; ++r) {
            int m = mt * 32 + (r & 3) + 8 * (r >> 2) + 4 * kg;
            Ls[m * 132 + colL] = (_Float16)fmaxf(acc[mt][r] + gbv, 0.f);
        }
    }
    __syncthreads();

    for (int u = tid; u < N * 16; u += 256) {
        int m = u >> 4, c = u & 15;
        half8_t v = ld_b8(&Ls[m * 132 + c * 8]);
        *(half8_t*)(out + (size_t)(b * N + m) * HT + colbase + c * 8) = v;
    }
}

__global__ __launch_bounds__(256) void adjmix_k(Args A, int l) {
    __shared__ __align__(16) _Float16 Ls[12800];
    int blk = blockIdx.x, tid = threadIdx.x;
    if (blk < 1024)
        adjmix_impl<NB_, 1, 2>(A.SupB, (const half8_t*)A.adjPB, A.b_gcb, A.Gb, blk, l, Ls, tid);
    else
        adjmix_impl<NF_, 3, 5>(A.SupF, (const half8_t*)A.adjPF, A.f_gcb, A.Gf, blk - 1024, l, Ls, tid);
}

// ---------------- conv2(l)(+bn+res): G -> trunk; block owns 2 chunks, dbuf + reg residual ----------------
__global__ __launch_bounds__(256, 6) void c2_k(Args A, int l) {
    __shared__ __align__(16) _Float16 Xs[2][72 * 68];
    int blk = blockIdx.x, tid = threadIdx.x;
    bool isB = blk < 2 * B_ * NB_;
    int j = isB ? blk : blk - 2 * B_ * NB_;
    int bn = j >> 1, half = j & 1;
    const _Float16* G = (isB ? A.Gb : A.Gf) + (size_t)bn * HT;
    _Float16* trunk   = (isB ? A.TrB : A.TrF) + (size_t)bn * HT;
    const half8_t* w2 = (const half8_t*)(A.W3 + (isB ? 110592 : 331776)) + (size_t)l * (K_ * 8 * H_);
    const float* b2l  = (isB ? A.B2 + 192 : A.B2 + 576) + l * H_;

    int ln = tid & 63;
    int w = __builtin_amdgcn_readfirstlane(tid >> 6);
    int ln31 = ln & 31, kg = ln >> 5;
    int ts = w & 1, ot = w >> 1;
    int trow = ts * 32;

    {
        SReg S;
        issue_stage(G, half * 2, tid, S);
        write_stage(Xs[0], tid, S);
    }
    __syncthreads();

#pragma unroll 1
    for (int i = 0; i < 2; ++i) {
        int tc = half * 2 + i;
        RReg R;
        issue_res(trunk, tc, trow, ln31, kg, ot, R);       // consumed at epilogue
        SReg Sn;
        if (i == 0) issue_stage(G, tc + 1, tid, Sn);       // loads in flight across K-loop

        f32x16 acc;
#pragma unroll
        for (int r = 0; r < 16; ++r) acc[r] = 0.f;
        conv_kloop(w2, Xs[i], trow, ln31, kg, ot, acc);

        if (i == 0) write_stage(Xs[1], tid, Sn);           // idle buffer, pre-barrier
        __syncthreads();   // conv B-reads done before overwriting mid rows

        // epilogue: y = acc + b2 + res -> Xs[i] mid rows (f16, same rounding as before)
        {
            _Float16* orow = Xs[i] + (size_t)(4 + trow + ln31) * 68;
#pragma unroll
            for (int rg = 0; rg < 4; ++rg) {
                int o0 = ot * 32 + rg * 8 + kg * 4;
                f32x4 bv = *(const f32x4*)(b2l + o0);
                half4_t rv = R.r[rg];
                half4_t hv;
#pragma unroll
                for (int jj = 0; jj < 4; ++jj)
                    hv[jj] = (_Float16)(acc[rg * 4 + jj] + bv[jj] + (float)rv[jj]);
                *(half4_t*)(orow + o0) = hv;
            }
        }
        __syncthreads();

        // copy new trunk chunk out (coalesced b128)
        _Float16* gout = trunk + (size_t)(tc * 64) * H_;
        const _Float16* srow = Xs[i] + 4 * 68;
#pragma unroll
        for (int k2 = 0; k2 < 2; ++k2) {
            int u2 = k2 * 256 + tid;
            int r = u2 >> 3, c = u2 & 7;
            half8_t v = ld_b8(srow + r * 68 + c * 8);
            *(half8_t*)(gout + (size_t)r * H_ + c * 8) = v;
        }
        if (i == 0) __syncthreads();   // ensure Xs[1] visible to all before next K-loop
    }
}

// ---------------- conv2(2,LAST): mean-pool partial -> feat; tail blocks = head (R6 verbatim) ----------------
__global__ __launch_bounds__(256, 8) void c2last_k(Args A) {
    __shared__ __align__(16) _Float16 Xs[72 * 68];
    __shared__ __align__(16) _Float16 Rs[64 * 68];
    int blk = blockIdx.x, tid = threadIdx.x;
    if (blk >= 2720) {             // head stream: 8 blocks
        int b = blk - 2720;
        if (tid < 64) {
            int c = tid;
            float w0 = A.head_w[c], w1 = A.head_w[64 + c], w2 = A.head_w[128 + c],
                  w3 = A.head_w[192 + c], w4 = A.head_w[256 + c], w5 = A.head_w[320 + c];
            float bias = A.head_b[c];
            float acc = 0.f;
            for (int t = 0; t < T_; ++t) {
                const float* xr = A.head_pose + ((size_t)b * T_ + t) * HP_;
                float s = fmaf(xr[0], w0, fmaf(xr[1], w1, fmaf(xr[2], w2,
                          fmaf(xr[3], w3, fmaf(xr[4], w4, fmaf(xr[5], w5, bias))))));
                acc += fmaxf(s, 0.f);
            }
            A.feat[(size_t)b * FEAT_DIM + NB_ * H_ + NF_ * H_ + c] = acc * (1.f / 256.f);
        }
        return;
    }
    constexpr int l = L_ - 1;
    bool isB = blk < 4 * B_ * NB_;
    int j = isB ? blk : blk - 4 * B_ * NB_;
    int bn = j >> 2, tc = j & 3;
    const _Float16* G = isB ? A.Gb : A.Gf;
    _Float16* trunk   = isB ? A.TrB : A.TrF;
    const half8_t* w2 = (const half8_t*)(A.W3 + (isB ? 110592 : 331776)) + (size_t)l * (K_ * 8 * H_);
    const float* b2l  = (isB ? A.B2 + 192 : A.B2 + 576) + l * H_;
    int N = isB ? NB_ : NF_;
    int fbase = isB ? 0 : NB_ * H_;

    stage_chunk64(G + (size_t)bn * HT, Xs, tc, tid);
    stage_res64(trunk + (size_t)bn * HT, Rs, tc, tid);
    __syncthreads();

    int ln = tid & 63;
    int w = __builtin_amdgcn_readfirstlane(tid >> 6);
    int ln31 = ln & 31, kg = ln >> 5;
    int ts = w & 1, ot = w >> 1;
    int trow = ts * 32;

    f32x16 acc;
#pragma unroll
    for (int r = 0; r < 16; ++r) acc[r] = 0.f;

    conv_kloop(w2, Xs, trow, ln31, kg, ot, acc);

    // mean-pool partial over this wave's 32 t: per-lane y then shfl over 32 lanes
    float sv[16];
    const _Float16* rrow = Rs + (size_t)(trow + ln31) * 68;
#pragma unroll
    for (int rg = 0; rg < 4; ++rg) {
        int o0 = ot * 32 + rg * 8 + kg * 4;
        f32x4 bv = *(const f32x4*)(b2l + o0);
        half4_t rv = *(const half4_t*)(rrow + o0);
#pragma unroll
        for (int jj = 0; jj < 4; ++jj) {
            int r = rg * 4 + jj;
            float s = acc[r] + bv[jj] + (float)rv[jj];
#pragma unroll
            for (int off = 1; off < 32; off <<= 1) s += __shfl_xor(s, off);
            sv[r] = s;
        }
    }
    __syncthreads();   // Xs reads done; reuse as reduction scratch
    float* red = (float*)Xs;   // [4 waves][32 o-local]
    if (ln31 == 0) {
#pragma unroll
        for (int r = 0; r < 16; ++r) {
            int olocal = (r & 3) + 8 * (r >> 2) + 4 * kg;
            red[w * 32 + olocal] = sv[r];
        }
    }
    __syncthreads();
    if (tid < 64) {
        int o = tid, ot2 = o >> 5, ol = o & 31;
        float s = red[(ot2 * 2) * 32 + ol] + red[(ot2 * 2 + 1) * 32 + ol];
        int b = bn / N, n = bn % N;
        atomicAdd(&A.feat[(size_t)b * FEAT_DIM + fbase + n * H_ + o], s * (1.f / 256.f));
    }
}

// ---------------- fusion layer 1 (5504 -> 256), split-K, all 8 batches per block ----------------
__global__ __launch_bounds__(256) void fus1_k(Args A) {
    __shared__ float fv[8][64];
    int blk = blockIdx.x;          // 86 = 43 ic * 2 khalf
    int ic = blk >> 1, kh = blk & 1;
    int base = ic * 128 + kh * 64;
    int tid = threadIdx.x;
    for (int u = tid; u < 8 * 64; u += 256) {
        int b = u >> 6, j = u & 63;
        fv[b][j] = A.feat[(size_t)b * FEAT_DIM + base + j];
    }
    __syncthreads();
    float acc[8];
#pragma unroll
    for (int b = 0; b < 8; ++b) acc[b] = 0.f;
    const float* wb = A.fus1_w + (size_t)base * 256 + tid;
    for (int i = 0; i < 64; ++i) {
        float wv = wb[(size_t)i * 256];
#pragma unroll
        for (int b = 0; b < 8; ++b) acc[b] = fmaf(fv[b][i], wv, acc[b]);
    }
#pragma unroll
    for (int b = 0; b < 8; ++b) atomicAdd(&A.p1[b * 256 + tid], acc[b]);
}

// ---------------- fusion tail ----------------
__global__ __launch_bounds__(256) void fus_tail_k(Args A) {
    __shared__ float s1[256], s2[128], s3[64];
    int b = blockIdx.x, tid = threadIdx.x;
    s1[tid] = fmaxf(A.p1[b * 256 + tid] + A.fus1_b[tid], 0.f);
    __syncthreads();
    if (tid < 128) {
        float acc = A.fus2_b[tid];
        for (int i = 0; i < 256; ++i) acc = fmaf(s1[i], A.fus2_w[i * 128 + tid], acc);
        s2[tid] = fmaxf(acc, 0.f);
    }
    __syncthreads();
    if (tid < 64) {
        float acc = A.fus3_b[tid];
        for (int i = 0; i < 128; ++i) acc = fmaf(s2[i], A.fus3_w[i * 64 + tid], acc);
        s3[tid] = fmaxf(acc, 0.f);
    }
    __syncthreads();
    if (tid < 5) {
        float acc = A.fus4_b[tid];
        for (int i = 0; i < 64; ++i) acc = fmaf(s3[i], A.fus4_w[i * 5 + tid], acc);
        A.out[b * 5 + tid] = acc;
    }
}

// ---------------- launch ----------------
extern "C" void kernel_launch(void* const* d_in, const int* in_sizes, int n_in,
                              void* d_out, int out_size, void* d_ws, size_t ws_size,
                              hipStream_t stream) {
    float* ws = (float*)d_ws;

    Args A;
    A.body_kps = (const float*)d_in[0];
    A.face_kps = (const float*)d_in[1];
    A.head_pose = (const float*)d_in[2];
    A.body_adj = (const float*)d_in[3];
    A.face_adj = (const float*)d_in[4];
    A.body_pw = (const float*)d_in[5];
    A.body_pb = (const float*)d_in[6];
    A.face_pw = (const float*)d_in[7];
    A.face_pb = (const float*)d_in[8];
    A.head_w = (const float*)d_in[9];
    A.head_b = (const float*)d_in[10];
    A.sb1 = ConvPrepSet{(const float*)d_in[11], (const float*)d_in[12], (const float*)d_in[13],
                        (const float*)d_in[14], (const float*)d_in[15], (const float*)d_in[16]};
    A.b_gcw = (const float*)d_in[17];
    A.b_gcb = (const float*)d_in[18];
    A.sb2 = ConvPrepSet{(const float*)d_in[19], (const float*)d_in[20], (const float*)d_in[21],
                        (const float*)d_in[22], (const float*)d_in[23], (const float*)d_in[24]};
    A.sf1 = ConvPrepSet{(const float*)d_in[25], (const float*)d_in[26], (const float*)d_in[27],
                        (const float*)d_in[28], (const float*)d_in[29], (const float*)d_in[30]};
    A.f_gcw = (const float*)d_in[31];
    A.f_gcb = (const float*)d_in[32];
    A.sf2 = ConvPrepSet{(const float*)d_in[33], (const float*)d_in[34], (const float*)d_in[35],
                        (const float*)d_in[36], (const float*)d_in[37], (const float*)d_in[38]};
    A.fus1_w = (const float*)d_in[39]; A.fus1_b = (const float*)d_in[40];
    A.fus2_w = (const float*)d_in[41]; A.fus2_b = (const float*)d_in[42];
    A.fus3_w = (const float*)d_in[43]; A.fus3_b = (const float*)d_in[44];
    A.fus4_w = (const float*)d_in[45]; A.fus4_b = (const float*)d_in[46];

    A.TrB  = (_Float16*)(ws + OFF_TB);
    A.TrF  = (_Float16*)(ws + OFF_TF);
    A.SupB = (_Float16*)(ws + OFF_SUPB);
    A.SupF = (_Float16*)(ws + OFF_SUPF);
    A.Gb   = (_Float16*)(ws + OFF_GB);
    A.Gf   = (_Float16*)(ws + OFF_GF);
    A.W3   = (_Float16*)(ws + OFF_W3);
    A.GW3  = (_Float16*)(ws + OFF_GW3);
    A.adjPB= (_Float16*)(ws + OFF_ADJPB);
    A.adjPF= (_Float16*)(ws + OFF_ADJPF);
    A.B2   = ws + OFF_B2;
    A.feat = ws + OFF_FEAT;
    A.p1   = ws + OFF_P1;
    A.out  = (float*)d_out;

    const int gconv = 4 * (B_ * NB_ + B_ * NF_);   // 2720 (bn x 4 t-chunks)
    const int gdb   = 2 * (B_ * NB_ + B_ * NF_);   // 1360 (bn x 2 halves, dbuf)

    prep_k<<<2038, 256, 0, stream>>>(A);
    projcm_k<<<gconv, 256, 0, stream>>>(A);            // proj + convmix(0)
    for (int l = 0; l < L_; ++l) {
        adjmix_k<<<2048, 256, 0, stream>>>(A, l);
        if (l < L_ - 1) {
            c2_k<<<gdb, 256, 0, stream>>>(A, l);       // conv2(l), dbuf 2-chunk
            cm_k<<<gdb, 256, 0, stream>>>(A, l + 1);   // convmix(l+1), dbuf 2-chunk
        } else {
            c2last_k<<<gconv + 8, 256, 0, stream>>>(A); // conv2(2)+pool + head
        }
    }
    fus1_k<<<86, 256, 0, stream>>>(A);
    fus_tail_k<<<8, 256, 0, stream>>>(A);
}

// Round 12
// 375.967 us; speedup vs baseline: 1.7952x; 1.3329x over previous
//
#include <hip/hip_runtime.h>

// ---------------- problem constants ----------------
constexpr int B_ = 8, T_ = 256, H_ = 64, L_ = 3, NB_ = 17, NF_ = 68, HP_ = 6, K_ = 9;
constexpr int FEAT_DIM = NB_ * H_ + NF_ * H_ + H_;   // 5504
constexpr int HT = H_ * T_;                          // 16384 per (b,n)

typedef _Float16 half4_t __attribute__((ext_vector_type(4)));
typedef _Float16 half8_t __attribute__((ext_vector_type(8)));
typedef float f32x16 __attribute__((ext_vector_type(16)));
typedef float f32x4 __attribute__((ext_vector_type(4)));

// ---------------- workspace layout (float units); activations f16 [bn][t][o] ----------------
constexpr size_t SZ_AB = (size_t)B_ * NB_ * HT;
constexpr size_t SZ_AF = (size_t)B_ * NF_ * HT;
constexpr size_t OFF_TB   = 0;
constexpr size_t OFF_TF   = OFF_TB + SZ_AB / 2;
constexpr size_t OFF_SUPB = OFF_TF + SZ_AF / 2;
constexpr size_t OFF_SUPF = OFF_SUPB + SZ_AB / 2;
constexpr size_t OFF_GB   = OFF_SUPF + SZ_AF / 2;
constexpr size_t OFF_GF   = OFF_GB + SZ_AB / 2;
constexpr size_t OFF_W3   = OFF_GF + SZ_AF / 2;      // 4 conv sets x 110592 f16
constexpr size_t OFF_GW3  = OFF_W3 + 4 * 55296;      // 2 x 12288 f16
constexpr size_t OFF_B2   = OFF_GW3 + 2 * 6144;      // 4 x 192 f32
constexpr size_t OFF_ADJPB= OFF_B2 + 768;            // 32x32 f16
constexpr size_t OFF_ADJPF= OFF_ADJPB + 512;         // 96x80 f16
constexpr size_t OFF_FEAT = OFF_ADJPF + 3840;        // 8x5504 f32
constexpr size_t OFF_P1   = OFF_FEAT + (size_t)B_ * FEAT_DIM;

struct ConvPrepSet { const float *w, *tb, *g, *bb, *m, *v; };

// ---------------- all pointers in one arg struct ----------------
struct Args {
    const float *body_kps, *face_kps, *head_pose, *body_adj, *face_adj;
    const float *body_pw, *body_pb, *face_pw, *face_pb, *head_w, *head_b;
    ConvPrepSet sb1, sb2, sf1, sf2;
    const float *b_gcw, *f_gcw, *b_gcb, *f_gcb;
    const float *fus1_w, *fus1_b, *fus2_w, *fus2_b, *fus3_w, *fus3_b, *fus4_w, *fus4_b;
    _Float16 *TrB, *TrF, *SupB, *SupF, *Gb, *Gf;
    _Float16 *W3, *GW3, *adjPB, *adjPF;
    float *B2, *p1, *feat;
    float *out;
};

// ---------------- small helpers ----------------
__device__ __forceinline__ half8_t ld_b8(const _Float16* p) {
    half4_t lo = *(const half4_t*)p;
    half4_t hi = *(const half4_t*)(p + 4);
    return __builtin_shufflevector(lo, hi, 0, 1, 2, 3, 4, 5, 6, 7);
}

__device__ __forceinline__ void st_b8(_Float16* p, half8_t v) {
    half4_t lo, hi;
#pragma unroll
    for (int j = 0; j < 4; ++j) { lo[j] = v[j]; hi[j] = v[4 + j]; }
    *(half4_t*)p = lo;
    *(half4_t*)(p + 4) = hi;
}

// stage f16 [t][o] 64-t chunk -> Xs[72][68]; rows 0..71 = t (tc*64-4 .. tc*64+67), OOB=0
__device__ __forceinline__ void stage_chunk64(const _Float16* __restrict__ xb,
                                              _Float16* __restrict__ Xs, int tc, int tid) {
    for (int u = tid; u < 72 * 8; u += 256) {
        int row = u >> 3, c = u & 7;
        int t = tc * 64 + row - 4;
        half8_t v;
        if (t >= 0 && t < T_) {
            v = *(const half8_t*)(xb + (size_t)t * H_ + c * 8);
        } else {
#pragma unroll
            for (int j = 0; j < 8; ++j) v[j] = (_Float16)0.f;
        }
        st_b8(&Xs[row * 68 + c * 8], v);
    }
}

// stage residual 64-t chunk rows [t][o] -> Rs[64][68] (t = tc*64 .. tc*64+63)
__device__ __forceinline__ void stage_res64(const _Float16* __restrict__ xb,
                                            _Float16* __restrict__ Rs, int tc, int tid) {
    for (int u = tid; u < 64 * 8; u += 256) {
        int row = u >> 3, c = u & 7;
        half8_t v = *(const half8_t*)(xb + (size_t)(tc * 64 + row) * H_ + c * 8);
        st_b8(&Rs[row * 68 + c * 8], v);
    }
}

// conv K-loop: 9 taps x 4 ks -> acc, wave covers 32 t-cols x 32 o (one o-tile)
__device__ __forceinline__ void conv_kloop(const half8_t* __restrict__ wl,
                                           const _Float16* __restrict__ Xs,
                                           int trow, int ln31, int kg, int ot,
                                           f32x16& acc) {
    const _Float16* xr0 = Xs + (size_t)(trow + ln31) * 68;
#pragma unroll
    for (int tap = 0; tap < K_; ++tap) {
#pragma unroll
        for (int ks = 0; ks < 4; ++ks) {
            int i8 = ks * 2 + kg;
            half8_t a = wl[(tap * 8 + i8) * H_ + ot * 32 + ln31];
            half8_t bf = ld_b8(xr0 + tap * 68 + i8 * 8);
            acc = __builtin_amdgcn_mfma_f32_32x32x16_f16(a, bf, acc, 0, 0, 0);
        }
    }
}

// ---------------- convmix core: Xs pre-staged -> sup 64-t chunk ----------------
// 4 waves: wave (ts = w&1, ot = w>>1) covers t-sub 32ts..32ts+32, o-tile 32ot..
__device__ void convmix_core(const half8_t* __restrict__ wl,   // w1 + layer offset
                             const float* __restrict__ b1l,    // b1 + l*H_
                             const half8_t* __restrict__ gl,   // gc + layer offset
                             _Float16* __restrict__ supb,      // sup + bn*HT
                             int tc, _Float16* __restrict__ Xs, int tid) {
    int ln = tid & 63;
    int w = __builtin_amdgcn_readfirstlane(tid >> 6);
    int ln31 = ln & 31, kg = ln >> 5;
    int ts = w & 1, ot = w >> 1;
    int trow = ts * 32;

    f32x16 acc;
#pragma unroll
    for (int r = 0; r < 16; ++r) acc[r] = 0.f;

    conv_kloop(wl, Xs, trow, ln31, kg, ot, acc);
    __syncthreads();

    // conv1 epilogue: bias+relu -> mid row Xs[4+t][o] (wave-own (ts,ot) region)
    _Float16* mrow = Xs + (size_t)(4 + trow + ln31) * 68;
#pragma unroll
    for (int rg = 0; rg < 4; ++rg) {
        int o0 = ot * 32 + rg * 8 + kg * 4;
        f32x4 bv = *(const f32x4*)(b1l + o0);
        half4_t hv;
#pragma unroll
        for (int j = 0; j < 4; ++j)
            hv[j] = (_Float16)fmaxf(acc[rg * 4 + j] + bv[j], 0.f);
        *(half4_t*)(mrow + o0) = hv;
    }
    __syncthreads();

    // channel mix (K=64): reads full mid rows (both o-halves)
    f32x16 acc2;
#pragma unroll
    for (int r = 0; r < 16; ++r) acc2[r] = 0.f;
#pragma unroll
    for (int ks = 0; ks < 4; ++ks) {
        int i8 = ks * 2 + kg;
        half8_t a = gl[i8 * H_ + ot * 32 + ln31];
        half8_t bf = ld_b8(mrow + i8 * 8);
        acc2 = __builtin_amdgcn_mfma_f32_32x32x16_f16(a, bf, acc2, 0, 0, 0);
    }
    __syncthreads();   // other o-wave may still be reading these rows

    // write acc2 -> mid rows (wave-own region), then coalesced b128 copy-out
#pragma unroll
    for (int rg = 0; rg < 4; ++rg) {
        int o0 = ot * 32 + rg * 8 + kg * 4;
        half4_t hv;
#pragma unroll
        for (int j = 0; j < 4; ++j)
            hv[j] = (_Float16)acc2[rg * 4 + j];
        *(half4_t*)(mrow + o0) = hv;
    }
    __syncthreads();
    _Float16* gout = supb + (size_t)(tc * 64) * H_;
    const _Float16* srow = Xs + 4 * 68;
#pragma unroll
    for (int k2 = 0; k2 < 2; ++k2) {
        int u = k2 * 256 + tid;     // 512 units: 64 rows x 8 col-groups
        int r = u >> 3, c = u & 7;
        half8_t v = ld_b8(srow + r * 68 + c * 8);
        *(half8_t*)(gout + (size_t)r * H_ + c * 8) = v;
    }
}

// ---------------- prep: fold BN into conv W; gcw pack; adj pad; zero p1/feat ----------------
__global__ __launch_bounds__(256) void prep_k(Args A) {
    int blk = blockIdx.x;
    int tid = threadIdx.x;
    if (blk < 1728) {                       // conv-weight fold: 4 sets x 432 blocks
        int set = blk / 432;
        int bx = blk % 432;
        ConvPrepSet s = (set == 0) ? A.sb1 : (set == 1) ? A.sb2 : (set == 2) ? A.sf1 : A.sf2;
        int idx = bx * 256 + tid;           // < 110592
        int k = idx % K_; int r = idx / K_;
        int i = r % H_; r /= H_;
        int o = r % H_; int l = r / H_;
        float sc = s.g[l * H_ + o] * rsqrtf(s.v[l * H_ + o] + 1e-5f);
        A.W3[(size_t)set * 110592 + ((((l * K_ + k) * 8 + (i >> 3)) * H_ + o) * 8) + (i & 7)]
            = (_Float16)(s.w[idx] * sc);
        if (i == 0 && k == 0)
            A.B2[set * 192 + l * H_ + o] =
                s.tb[l * H_ + o] * sc + s.bb[l * H_ + o] - s.m[l * H_ + o] * sc;
    } else if (blk < 1824) {                // gc-weight pack: 2 sets x 48 blocks
        int set = (blk - 1728) / 48;
        int bx = (blk - 1728) % 48;
        const float* gw = set ? A.f_gcw : A.b_gcw;
        int idx = bx * 256 + tid;           // < 12288
        int o = idx % H_; int r = idx / H_;
        int c = r % H_; int l = r / H_;
        A.GW3[(size_t)set * 12288 + (((l * 8 + (c >> 3)) * H_ + o) * 8) + (c & 7)]
            = (_Float16)gw[idx];
    } else {                                // misc: adj pad + zero p1/feat
        int idx = (blk - 1824) * 256 + tid;
        if (idx < 1024) {
            int m = idx >> 5, k = idx & 31;
            A.adjPB[idx] = (m < NB_ && k < NB_) ? (_Float16)A.body_adj[m * NB_ + k] : (_Float16)0.f;
        } else if (idx < 8704) {
            int j = idx - 1024;
            int m = j / 80, k = j % 80;
            A.adjPF[j] = (m < NF_ && k < NF_) ? (_Float16)A.face_adj[m * NF_ + k] : (_Float16)0.f;
        } else if (idx < 10752) {
            A.p1[idx - 8704] = 0.f;
        } else if (idx < 10752 + B_ * FEAT_DIM) {
            A.feat[idx - 10752] = 0.f;
        }
    }
}

// ---------------- fused proj + convmix(l=0): block = (bn, 64-t chunk) ----------------
__global__ __launch_bounds__(256, 8) void projcm_k(Args A) {
    __shared__ __align__(16) _Float16 Xs[72 * 68];
    int blk = blockIdx.x, tid = threadIdx.x;
    bool isB = blk < 4 * B_ * NB_;
    int j = isB ? blk : blk - 4 * B_ * NB_;
    int bn = j >> 2, tc = j & 3;
    const float* kps = isB ? A.body_kps : A.face_kps;
    const float* pw  = isB ? A.body_pw  : A.face_pw;
    const float* pb  = isB ? A.body_pb  : A.face_pb;
    _Float16* trunk  = isB ? A.TrB : A.TrF;
    int N = isB ? NB_ : NF_;
    int b = bn / N, n = bn % N;

    // proj: fill Xs rows 0..71 (incl. halo recompute); global write for owned rows only
    if (tid < 144) {
        int row = tid >> 1, hf = tid & 1;       // 32 channels per unit
        int t = tc * 64 + row - 4;
        _Float16* xr = Xs + row * 68 + hf * 32;
        if (t >= 0 && t < T_) {
            float x0 = kps[((size_t)b * T_ + t) * (N * 2) + n * 2 + 0];
            float x1 = kps[((size_t)b * T_ + t) * (N * 2) + n * 2 + 1];
            bool own = (row >= 4 && row < 68);
            _Float16* ob = trunk + (size_t)bn * HT + (size_t)t * H_ + hf * 32;
#pragma unroll
            for (int cg2 = 0; cg2 < 4; ++cg2) {
                half8_t v;
#pragma unroll
                for (int jj = 0; jj < 8; ++jj) {
                    int c = hf * 32 + cg2 * 8 + jj;
                    v[jj] = (_Float16)fmaf(x0, pw[c], fmaf(x1, pw[H_ + c], pb[c]));
                }
                st_b8(xr + cg2 * 8, v);
                if (own) *(half8_t*)(ob + cg2 * 8) = v;
            }
        } else {
            half8_t z;
#pragma unroll
            for (int jj = 0; jj < 8; ++jj) z[jj] = (_Float16)0.f;
            st_b8(xr, z);
            st_b8(xr + 8, z);
            st_b8(xr + 16, z);
            st_b8(xr + 24, z);
        }
    }
    __syncthreads();

    const half8_t* w1 = (const half8_t*)(A.W3 + (isB ? 0 : 221184));     // l=0 slice
    const float* b1l  = isB ? A.B2 : A.B2 + 384;
    const half8_t* gl = (const half8_t*)(A.GW3 + (isB ? 0 : 12288));
    _Float16* supb = (isB ? A.SupB : A.SupF) + (size_t)bn * HT;
    convmix_core(w1, b1l, gl, supb, tc, Xs, tid);
}

// ---------------- convmix(l): trunk -> sup ----------------
__global__ __launch_bounds__(256, 8) void cm_k(Args A, int l) {
    __shared__ __align__(16) _Float16 Xs[72 * 68];
    int blk = blockIdx.x, tid = threadIdx.x;
    bool isB = blk < 4 * B_ * NB_;
    int j = isB ? blk : blk - 4 * B_ * NB_;
    int bn = j >> 2, tc = j & 3;
    const _Float16* trunk = isB ? A.TrB : A.TrF;

    stage_chunk64(trunk + (size_t)bn * HT, Xs, tc, tid);
    __syncthreads();

    const half8_t* w1 = (const half8_t*)(A.W3 + (isB ? 0 : 221184)) + (size_t)l * (K_ * 8 * H_);
    const float* b1l  = (isB ? A.B2 : A.B2 + 384) + l * H_;
    const half8_t* gl = (const half8_t*)(A.GW3 + (isB ? 0 : 12288)) + (size_t)l * (8 * H_);
    _Float16* supb = (isB ? A.SupB : A.SupF) + (size_t)bn * HT;
    convmix_core(w1, b1l, gl, supb, tc, Xs, tid);
}

// ---------------- adjmix: out = relu(adj @ sup + gb), LDS-transposed b128 output ----------------
template <int N, int MT, int KS>
__device__ void adjmix_impl(const _Float16* __restrict__ sup,
                            const half8_t* __restrict__ adjP,
                            const float* __restrict__ gb,
                            _Float16* __restrict__ out,
                            int blk, int l, _Float16* Ls, int tid) {
    constexpr int KP = KS * 16;
    constexpr int PITCH = KP + 4;
    int b = blk >> 7, cb = blk & 127;
    int colbase = cb * 128;

    for (int u = tid; u < KP * 16; u += 256) {
        int n = u >> 4, cs = u & 15;
        half8_t v;
        if (n < N) v = *(const half8_t*)(sup + (size_t)(b * N + n) * HT + colbase + cs * 8);
        else {
#pragma unroll
            for (int j = 0; j < 8; ++j) v[j] = (_Float16)0.f;
        }
#pragma unroll
        for (int j = 0; j < 8; ++j) Ls[(cs * 8 + j) * PITCH + n] = v[j];
    }
    __syncthreads();

    int ln = tid & 63;
    int w = __builtin_amdgcn_readfirstlane(tid >> 6);
    int ln31 = ln & 31, kg = ln >> 5;
    int colL = w * 32 + ln31;

    f32x16 acc[MT];
#pragma unroll
    for (int mt = 0; mt < MT; ++mt)
#pragma unroll
        for (int r = 0; r < 16; ++r) acc[mt][r] = 0.f;

#pragma unroll
    for (int ks = 0; ks < KS; ++ks) {
        half8_t bf = ld_b8(&Ls[colL * PITCH + ks * 16 + kg * 8]);
#pragma unroll
        for (int mt = 0; mt < MT; ++mt) {
            half8_t af = adjP[(size_t)(mt * 32 + ln31) * (KP / 8) + ks * 2 + kg];
            acc[mt] = __builtin_amdgcn_mfma_f32_32x32x16_f16(af, bf, acc[mt], 0, 0, 0);
        }
    }
    __syncthreads();   // staging reads done; reuse Ls as [m][132] out-transpose buffer

    float gbv = gb[l * H_ + (colL & 63)];   // [t][o] layout: o = col & 63
#pragma unroll
    for (int mt = 0; mt < MT; ++mt) {
#pragma unroll
        for (int r = 0; r < 16; ++r) {
            int m = mt * 32 + (r & 3) + 8 * (r >> 2) + 4 * kg;
            Ls[m * 132 + colL] = (_Float16)fmaxf(acc[mt][r] + gbv, 0.f);
        }
    }
    __syncthreads();

    for (int u = tid; u < N * 16; u += 256) {
        int m = u >> 4, c = u & 15;
        half8_t v = ld_b8(&Ls[m * 132 + c * 8]);
        *(half8_t*)(out + (size_t)(b * N + m) * HT + colbase + c * 8) = v;
    }
}

__global__ __launch_bounds__(256) void adjmix_k(Args A, int l) {
    __shared__ __align__(16) _Float16 Ls[12800];
    int blk = blockIdx.x, tid = threadIdx.x;
    if (blk < 1024)
        adjmix_impl<NB_, 1, 2>(A.SupB, (const half8_t*)A.adjPB, A.b_gcb, A.Gb, blk, l, Ls, tid);
    else
        adjmix_impl<NF_, 3, 5>(A.SupF, (const half8_t*)A.adjPF, A.f_gcb, A.Gf, blk - 1024, l, Ls, tid);
}

// ---------------- conv2(l)(+bn+res): G -> trunk ----------------
__global__ __launch_bounds__(256, 8) void c2_k(Args A, int l) {
    __shared__ __align__(16) _Float16 Xs[72 * 68];
    __shared__ __align__(16) _Float16 Rs[64 * 68];
    int blk = blockIdx.x, tid = threadIdx.x;
    bool isB = blk < 4 * B_ * NB_;
    int j = isB ? blk : blk - 4 * B_ * NB_;
    int bn = j >> 2, tc = j & 3;
    const _Float16* G = isB ? A.Gb : A.Gf;
    _Float16* trunk   = isB ? A.TrB : A.TrF;
    const half8_t* w2 = (const half8_t*)(A.W3 + (isB ? 110592 : 331776)) + (size_t)l * (K_ * 8 * H_);
    const float* b2l  = (isB ? A.B2 + 192 : A.B2 + 576) + l * H_;

    stage_chunk64(G + (size_t)bn * HT, Xs, tc, tid);
    stage_res64(trunk + (size_t)bn * HT, Rs, tc, tid);
    __syncthreads();

    int ln = tid & 63;
    int w = __builtin_amdgcn_readfirstlane(tid >> 6);
    int ln31 = ln & 31, kg = ln >> 5;
    int ts = w & 1, ot = w >> 1;
    int trow = ts * 32;

    f32x16 acc;
#pragma unroll
    for (int r = 0; r < 16; ++r) acc[r] = 0.f;

    conv_kloop(w2, Xs, trow, ln31, kg, ot, acc);
    __syncthreads();   // all conv B-reads done before overwriting Xs rows

    // epilogue: y = acc + b2 + res -> Xs[4+t][o] (f16, same rounding as before)
    {
        _Float16* orow = Xs + (size_t)(4 + trow + ln31) * 68;
        const _Float16* rrow = Rs + (size_t)(trow + ln31) * 68;
#pragma unroll
        for (int rg = 0; rg < 4; ++rg) {
            int o0 = ot * 32 + rg * 8 + kg * 4;
            f32x4 bv = *(const f32x4*)(b2l + o0);
            half4_t rv = *(const half4_t*)(rrow + o0);
            half4_t hv;
#pragma unroll
            for (int jj = 0; jj < 4; ++jj)
                hv[jj] = (_Float16)(acc[rg * 4 + jj] + bv[jj] + (float)rv[jj]);
            *(half4_t*)(orow + o0) = hv;
        }
    }
    __syncthreads();

    // copy new trunk chunk out
    _Float16* gout = trunk + (size_t)bn * HT + (size_t)(tc * 64) * H_;
    const _Float16* srow = Xs + 4 * 68;
#pragma unroll
    for (int k2 = 0; k2 < 2; ++k2) {
        int u = k2 * 256 + tid;
        int r = u >> 3, c = u & 7;
        half8_t v = ld_b8(srow + r * 68 + c * 8);
        *(half8_t*)(gout + (size_t)r * H_ + c * 8) = v;
    }
}

// ---------------- conv2(2,LAST): mean-pool partial -> feat; tail blocks = head ----------------
__global__ __launch_bounds__(256, 8) void c2last_k(Args A) {
    __shared__ __align__(16) _Float16 Xs[72 * 68];
    __shared__ __align__(16) _Float16 Rs[64 * 68];
    int blk = blockIdx.x, tid = threadIdx.x;
    if (blk >= 2720) {             // head stream: 8 blocks
        int b = blk - 2720;
        if (tid < 64) {
            int c = tid;
            float w0 = A.head_w[c], w1 = A.head_w[64 + c], w2 = A.head_w[128 + c],
                  w3 = A.head_w[192 + c], w4 = A.head_w[256 + c], w5 = A.head_w[320 + c];
            float bias = A.head_b[c];
            float acc = 0.f;
            for (int t = 0; t < T_; ++t) {
                const float* xr = A.head_pose + ((size_t)b * T_ + t) * HP_;
                float s = fmaf(xr[0], w0, fmaf(xr[1], w1, fmaf(xr[2], w2,
                          fmaf(xr[3], w3, fmaf(xr[4], w4, fmaf(xr[5], w5, bias))))));
                acc += fmaxf(s, 0.f);
            }
            A.feat[(size_t)b * FEAT_DIM + NB_ * H_ + NF_ * H_ + c] = acc * (1.f / 256.f);
        }
        return;
    }
    constexpr int l = L_ - 1;
    bool isB = blk < 4 * B_ * NB_;
    int j = isB ? blk : blk - 4 * B_ * NB_;
    int bn = j >> 2, tc = j & 3;
    const _Float16* G = isB ? A.Gb : A.Gf;
    _Float16* trunk   = isB ? A.TrB : A.TrF;
    const half8_t* w2 = (const half8_t*)(A.W3 + (isB ? 110592 : 331776)) + (size_t)l * (K_ * 8 * H_);
    const float* b2l  = (isB ? A.B2 + 192 : A.B2 + 576) + l * H_;
    int N = isB ? NB_ : NF_;
    int fbase = isB ? 0 : NB_ * H_;

    stage_chunk64(G + (size_t)bn * HT, Xs, tc, tid);
    stage_res64(trunk + (size_t)bn * HT, Rs, tc, tid);
    __syncthreads();

    int ln = tid & 63;
    int w = __builtin_amdgcn_readfirstlane(tid >> 6);
    int ln31 = ln & 31, kg = ln >> 5;
    int ts = w & 1, ot = w >> 1;
    int trow = ts * 32;

    f32x16 acc;
#pragma unroll
    for (int r = 0; r < 16; ++r) acc[r] = 0.f;

    conv_kloop(w2, Xs, trow, ln31, kg, ot, acc);

    // mean-pool partial over this wave's 32 t: per-lane y then shfl over 32 lanes
    float sv[16];
    const _Float16* rrow = Rs + (size_t)(trow + ln31) * 68;
#pragma unroll
    for (int rg = 0; rg < 4; ++rg) {
        int o0 = ot * 32 + rg * 8 + kg * 4;
        f32x4 bv = *(const f32x4*)(b2l + o0);
        half4_t rv = *(const half4_t*)(rrow + o0);
#pragma unroll
        for (int jj = 0; jj < 4; ++jj) {
            int r = rg * 4 + jj;
            float s = acc[r] + bv[jj] + (float)rv[jj];
#pragma unroll
            for (int off = 1; off < 32; off <<= 1) s += __shfl_xor(s, off);
            sv[r] = s;
        }
    }
    __syncthreads();   // Xs reads done; reuse as reduction scratch
    float* red = (float*)Xs;   // [4 waves][32 o-local]
    if (ln31 == 0) {
#pragma unroll
        for (int r = 0; r < 16; ++r) {
            int olocal = (r & 3) + 8 * (r >> 2) + 4 * kg;
            red[w * 32 + olocal] = sv[r];
        }
    }
    __syncthreads();
    if (tid < 64) {
        int o = tid, ot2 = o >> 5, ol = o & 31;
        float s = red[(ot2 * 2) * 32 + ol] + red[(ot2 * 2 + 1) * 32 + ol];
        int b = bn / N, n = bn % N;
        atomicAdd(&A.feat[(size_t)b * FEAT_DIM + fbase + n * H_ + o], s * (1.f / 256.f));
    }
}

// ---------------- fusion layer 1 (5504 -> 256), split-K, all 8 batches per block ----------------
__global__ __launch_bounds__(256) void fus1_k(Args A) {
    __shared__ float fv[8][64];
    int blk = blockIdx.x;          // 86 = 43 ic * 2 khalf
    int ic = blk >> 1, kh = blk & 1;
    int base = ic * 128 + kh * 64;
    int tid = threadIdx.x;
    for (int u = tid; u < 8 * 64; u += 256) {
        int b = u >> 6, j = u & 63;
        fv[b][j] = A.feat[(size_t)b * FEAT_DIM + base + j];
    }
    __syncthreads();
    float acc[8];
#pragma unroll
    for (int b = 0; b < 8; ++b) acc[b] = 0.f;
    const float* wb = A.fus1_w + (size_t)base * 256 + tid;
    for (int i = 0; i < 64; ++i) {
        float wv = wb[(size_t)i * 256];
#pragma unroll
        for (int b = 0; b < 8; ++b) acc[b] = fmaf(fv[b][i], wv, acc[b]);
    }
#pragma unroll
    for (int b = 0; b < 8; ++b) atomicAdd(&A.p1[b * 256 + tid], acc[b]);
}

// ---------------- fusion tail ----------------
__global__ __launch_bounds__(256) void fus_tail_k(Args A) {
    __shared__ float s1[256], s2[128], s3[64];
    int b = blockIdx.x, tid = threadIdx.x;
    s1[tid] = fmaxf(A.p1[b * 256 + tid] + A.fus1_b[tid], 0.f);
    __syncthreads();
    if (tid < 128) {
        float acc = A.fus2_b[tid];
        for (int i = 0; i < 256; ++i) acc = fmaf(s1[i], A.fus2_w[i * 128 + tid], acc);
        s2[tid] = fmaxf(acc, 0.f);
    }
    __syncthreads();
    if (tid < 64) {
        float acc = A.fus3_b[tid];
        for (int i = 0; i < 128; ++i) acc = fmaf(s2[i], A.fus3_w[i * 64 + tid], acc);
        s3[tid] = fmaxf(acc, 0.f);
    }
    __syncthreads();
    if (tid < 5) {
        float acc = A.fus4_b[tid];
        for (int i = 0; i < 64; ++i) acc = fmaf(s3[i], A.fus4_w[i * 5 + tid], acc);
        A.out[b * 5 + tid] = acc;
    }
}

// ---------------- launch ----------------
extern "C" void kernel_launch(void* const* d_in, const int* in_sizes, int n_in,
                              void* d_out, int out_size, void* d_ws, size_t ws_size,
                              hipStream_t stream) {
    float* ws = (float*)d_ws;

    Args A;
    A.body_kps = (const float*)d_in[0];
    A.face_kps = (const float*)d_in[1];
    A.head_pose = (const float*)d_in[2];
    A.body_adj = (const float*)d_in[3];
    A.face_adj = (const float*)d_in[4];
    A.body_pw = (const float*)d_in[5];
    A.body_pb = (const float*)d_in[6];
    A.face_pw = (const float*)d_in[7];
    A.face_pb = (const float*)d_in[8];
    A.head_w = (const float*)d_in[9];
    A.head_b = (const float*)d_in[10];
    A.sb1 = ConvPrepSet{(const float*)d_in[11], (const float*)d_in[12], (const float*)d_in[13],
                        (const float*)d_in[14], (const float*)d_in[15], (const float*)d_in[16]};
    A.b_gcw = (const float*)d_in[17];
    A.b_gcb = (const float*)d_in[18];
    A.sb2 = ConvPrepSet{(const float*)d_in[19], (const float*)d_in[20], (const float*)d_in[21],
                        (const float*)d_in[22], (const float*)d_in[23], (const float*)d_in[24]};
    A.sf1 = ConvPrepSet{(const float*)d_in[25], (const float*)d_in[26], (const float*)d_in[27],
                        (const float*)d_in[28], (const float*)d_in[29], (const float*)d_in[30]};
    A.f_gcw = (const float*)d_in[31];
    A.f_gcb = (const float*)d_in[32];
    A.sf2 = ConvPrepSet{(const float*)d_in[33], (const float*)d_in[34], (const float*)d_in[35],
                        (const float*)d_in[36], (const float*)d_in[37], (const float*)d_in[38]};
    A.fus1_w = (const float*)d_in[39]; A.fus1_b = (const float*)d_in[40];
    A.fus2_w = (const float*)d_in[41]; A.fus2_b = (const float*)d_in[42];
    A.fus3_w = (const float*)d_in[43]; A.fus3_b = (const float*)d_in[44];
    A.fus4_w = (const float*)d_in[45]; A.fus4_b = (const float*)d_in[46];

    A.TrB  = (_Float16*)(ws + OFF_TB);
    A.TrF  = (_Float16*)(ws + OFF_TF);
    A.SupB = (_Float16*)(ws + OFF_SUPB);
    A.SupF = (_Float16*)(ws + OFF_SUPF);
    A.Gb   = (_Float16*)(ws + OFF_GB);
    A.Gf   = (_Float16*)(ws + OFF_GF);
    A.W3   = (_Float16*)(ws + OFF_W3);
    A.GW3  = (_Float16*)(ws + OFF_GW3);
    A.adjPB= (_Float16*)(ws + OFF_ADJPB);
    A.adjPF= (_Float16*)(ws + OFF_ADJPF);
    A.B2   = ws + OFF_B2;
    A.feat = ws + OFF_FEAT;
    A.p1   = ws + OFF_P1;
    A.out  = (float*)d_out;

    const int gconv = 4 * (B_ * NB_ + B_ * NF_);   // 2720 (bn x 4 t-chunks)

    prep_k<<<2038, 256, 0, stream>>>(A);
    projcm_k<<<gconv, 256, 0, stream>>>(A);            // proj + convmix(0)
    for (int l = 0; l < L_; ++l) {
        adjmix_k<<<2048, 256, 0, stream>>>(A, l);
        if (l < L_ - 1) {
            c2_k<<<gconv, 256, 0, stream>>>(A, l);     // conv2(l)
            cm_k<<<gconv, 256, 0, stream>>>(A, l + 1); // convmix(l+1)
        } else {
            c2last_k<<<gconv + 8, 256, 0, stream>>>(A); // conv2(2)+pool + head
        }
    }
    fus1_k<<<86, 256, 0, stream>>>(A);
    fus_tail_k<<<8, 256, 0, stream>>>(A);
}